// Round 11
// baseline (164.183 us; speedup 1.0000x reference)
//
#include <hip/hip_runtime.h>
#include <hip/hip_bf16.h>
#include <stdint.h>

// MoE dilated conv FFN: E=8, DM=512, DH=1024, K=3, DIL=2, PAD=2, N=128, L=128.
// R11 = R10 with the staging-count bug fixed (SLD was 32/NW: staged 32KB into a
// 16.9KB LDS buffer -> corruption; correct is 8/NW: 512 16B-units per 8KB chunk).
// Serial-sum model (time = matrix + LDS + sync; no overlap in R2..R9) ->
// maximize FLOP per LDS byte. Wave tile 64x128 (full L): B frags (8/tap) from
// LDS (XOR-swizzled, staged via global_load_lds, dbuf 2x8.4KB); A frags DIRECT
// global->VGPR (1KB coalesced dwordx4 from unswizzled w_prep), register-
// prefetched one chunk ahead (staggered per-tap). R_LDS = 64 FLOP/B (was 32).
// One bare barrier + VMW(12) per chunk (drains B-stage only; A prefetch stays
// in flight; sched_barrier pins B-before-A issue order so vmcnt math holds).
// conv1: 4-wave 256-row blocks; conv2: 2-wave 128-row blocks; both 512 blocks.

typedef __attribute__((ext_vector_type(8))) short short8;   // 8 bf16 = 4 VGPR
typedef __attribute__((ext_vector_type(4))) float f32x4;

#define DMV 512
#define DHV 1024

// workspace layout (bytes)
#define OFF_X   0ull                 // x_prep  [128][16][128][4][8] bf16 = 16 MB
#define OFF_H   (16ull << 20)        // h_prep  [128][32][128][4][8] bf16 = 32 MB
#define OFF_W1  (48ull << 20)        // w1_prep [8][16][8][3][128][4][8] = 24 MB
#define OFF_W2  (72ull << 20)        // w2_prep [8][32][4][3][128][4][8] = 24 MB

#define VMW(n) asm volatile("s_waitcnt vmcnt(" #n ")" ::: "memory")
#define SB __builtin_amdgcn_sched_barrier(0)

__device__ __forceinline__ uint16_t f2bf(float f) {
  uint32_t u = __builtin_bit_cast(uint32_t, f);
  uint32_t r = (u + 0x7FFFu + ((u >> 16) & 1u)) >> 16;  // RTNE
  return (uint16_t)r;
}

__device__ __forceinline__ void async_copy16(const void* g, void* l) {
  __builtin_amdgcn_global_load_lds(
      (const __attribute__((address_space(1))) uint32_t*)g,
      (__attribute__((address_space(3))) uint32_t*)l, 16, 0, 0);
}

__device__ __forceinline__ float gelu_f(float x) {
  float u = 0.7978845608028654f * (x + 0.044715f * x * x * x);
  float t = __expf(2.0f * u);
  float th = 1.0f - 2.0f / (t + 1.0f);
  return 0.5f * x * (1.0f + th);
}

// ---- prep_x: block = (s, cc) transposes a [32ch][128L] f32 tile via LDS.
// out chunk(s,cc,l,sub): c = cc*32 + ((sub^fl)&3)*8 + j, fl = ((l+2)>>1)&3.
__global__ __launch_bounds__(256) void prep_x_t(const float* __restrict__ inp,
                                                uint16_t* __restrict__ xp) {
  uint32_t b = blockIdx.x;              // 2048 = 128 s x 16 cc
  uint32_t s = b >> 4, cc = b & 15u;
  __shared__ uint16_t xs[32][132];
  uint32_t t = threadIdx.x;
  const float* src0 = inp + ((size_t)s * DMV + cc * 32u) * 128u;
#pragma unroll
  for (int i = 0; i < 4; ++i) {
    uint32_t idx = (uint32_t)i * 256u + t;
    uint32_t ch = idx >> 5, l4 = idx & 31u;
    float4 f = *(const float4*)(src0 + ch * 128u + l4 * 4u);
    uint2 pk;
    pk.x = (uint32_t)f2bf(f.x) | ((uint32_t)f2bf(f.y) << 16);
    pk.y = (uint32_t)f2bf(f.z) | ((uint32_t)f2bf(f.w) << 16);
    *(uint2*)&xs[ch][l4 * 4u] = pk;
  }
  __syncthreads();
  uint32_t l = t >> 1, half = t & 1u;
  uint32_t fl = ((l + 2u) >> 1) & 3u;
#pragma unroll
  for (int hi = 0; hi < 2; ++hi) {
    uint32_t sub = half * 2u + (uint32_t)hi;
    uint32_t cg = (sub ^ fl) & 3u;
    uint32_t pk[4];
#pragma unroll
    for (int p2 = 0; p2 < 4; ++p2) {
      uint32_t c0 = cg * 8u + (uint32_t)p2 * 2u;
      pk[p2] = (uint32_t)xs[c0][l] | ((uint32_t)xs[c0 + 1][l] << 16);
    }
    uint4 v; v.x = pk[0]; v.y = pk[1]; v.z = pk[2]; v.w = pk[3];
    size_t slot = (((size_t)s * 16u + cc) * 128u + l) * 4u + sub;
    *(uint4*)(xp + slot * 8u) = v;
  }
}

// ---- prep_w: thread = (e, o, cg) reads 12 contiguous floats (4ch x 3 taps).
// UNSWIZZLED: wp [e][cc][mt][k][row][sub][8] (A read direct global->VGPR).
template <int LOGCG, int LOGO>
__global__ __launch_bounds__(256) void prep_w_c(const float* __restrict__ w,
                                                uint16_t* __restrict__ wp) {
  constexpr uint32_t C = 4u << LOGCG;
  constexpr uint32_t CCn = C >> 5;
  constexpr uint32_t MTn = 1u << (LOGO - 7);
  uint32_t t = blockIdx.x * 256u + threadIdx.x;
  uint32_t cg = t & ((1u << LOGCG) - 1u);
  uint32_t o = (t >> LOGCG) & ((1u << LOGO) - 1u);
  uint32_t e = t >> (LOGCG + LOGO);
  uint32_t row = o & 127u, mt = o >> 7;
  const float* src = w + (((size_t)(e << LOGO) + o) * C + cg * 4u) * 3u;
  float4 f0 = *(const float4*)(src);
  float4 f1 = *(const float4*)(src + 4);
  float4 f2 = *(const float4*)(src + 8);
  uint32_t cc = cg >> 3;
  uint32_t sub = (cg >> 1) & 3u;
  uint32_t j0 = (cg & 1u) * 4u;
  size_t base = (((size_t)e * CCn + cc) * MTn + mt) * 3u;
  uint2 q;
  q.x = (uint32_t)f2bf(f0.x) | ((uint32_t)f2bf(f0.w) << 16);
  q.y = (uint32_t)f2bf(f1.z) | ((uint32_t)f2bf(f2.y) << 16);
  *(uint2*)(wp + ((base + 0u) * 128u + row) * 32u + sub * 8u + j0) = q;
  q.x = (uint32_t)f2bf(f0.y) | ((uint32_t)f2bf(f1.x) << 16);
  q.y = (uint32_t)f2bf(f1.w) | ((uint32_t)f2bf(f2.z) << 16);
  *(uint2*)(wp + ((base + 1u) * 128u + row) * 32u + sub * 8u + j0) = q;
  q.x = (uint32_t)f2bf(f0.z) | ((uint32_t)f2bf(f1.y) << 16);
  q.y = (uint32_t)f2bf(f2.x) | ((uint32_t)f2bf(f2.w) << 16);
  *(uint2*)(wp + ((base + 2u) * 128u + row) * 32u + sub * 8u + j0) = q;
}

// conv: wave tile 64 rows x 128 L. PHASE 1: 4-wave 256-row blocks, CC=16,
// gelu+bf16 -> h_prep (swizzled). PHASE 2: 2-wave 128-row blocks, CC=32 -> f32.
template <int PHASE>
__global__ __launch_bounds__(PHASE == 1 ? 256 : 128, 2) void conv_mfma(
    const uint16_t* __restrict__ bprep, const uint16_t* __restrict__ wprep,
    const float* __restrict__ bias, const int* __restrict__ cnt,
    uint16_t* __restrict__ hout, float* __restrict__ fout) {
  constexpr int CC  = (PHASE == 1) ? 16 : 32;   // Cin/32
  constexpr int MTP = (PHASE == 1) ? 8 : 4;     // 128-row prep tiles
  constexpr int NW  = (PHASE == 1) ? 4 : 2;     // waves/block
  constexpr int NT  = NW * 64;
  constexpr int SLD = 8 / NW;                   // B-stage loads/thread (8KB total)
  constexpr int OO  = (PHASE == 1) ? DHV : DMV;

  // XCD map: mt = xcd>>1 (weights/XCD ~3.8MB, L2-fit), 64 contiguous samples
  uint32_t b = blockIdx.x;                      // 512 blocks
  uint32_t xcd = b & 7u, i = b >> 3;            // i in 0..63
  const int s = (int)((xcd & 1u) * 64u + i);
  const int mt = (int)(xcd >> 1);               // 0..3
  const int mtBase = (PHASE == 1) ? mt * 2 : mt;
  int e = 0;
  { int cum = cnt[0]; while (s >= cum && e < 7) { ++e; cum += cnt[e]; } }
  const int tid = threadIdx.x;
  const int lane = tid & 63;
  const int wv = tid >> 6;
  const int l15 = lane & 15, kg = lane >> 4;

  __shared__ __align__(16) uint8_t lds[2 * 8448];   // B only, dbuf

  // per-lane A base (unswizzled prep: [k][row][sub(kg)][8])
  const size_t AST = (size_t)MTP * 12288;           // chunk stride (u16)
  const uint16_t* wLane = wprep + ((size_t)e * CC * MTP + mtBase) * 12288
                          + (uint32_t)(l15 * 32 + kg * 8);
  const uint16_t* xBase = bprep + (size_t)s * CC * 4096;

  // zero pad rows l' = 0,1,130,131 (both B buffers) — persist
  if (tid < 32) {
    uint32_t n = (uint32_t)tid >> 4, ri = ((uint32_t)tid >> 2) & 3u, sb = (uint32_t)tid & 3u;
    uint32_t rowByte = (ri < 2) ? ri * 64u : (8320u + (ri - 2) * 64u);
    uint4 z = make_uint4(0, 0, 0, 0);
    *(uint4*)(lds + n * 8448u + rowByte + sb * 16u) = z;
  }

  // prologue: stage B(0), load A(0) -> aA, full drain once
  {
    uint8_t* bw = lds + 128u;
#pragma unroll
    for (int t = 0; t < SLD; ++t)
      async_copy16(xBase + (t * NT + tid) * 8, bw + (uint32_t)(t * NT + tid) * 16);
  }
  SB;
  short8 aA[3][4], aB[3][4];
#pragma unroll
  for (int k = 0; k < 3; ++k)
#pragma unroll
    for (int q = 0; q < 4; ++q) {
      uint32_t rows = (uint32_t)(wv * 64 + q * 16);
      aA[k][q] = *(const short8*)(wLane + (rows >> 7) * 12288u +
                                  ((uint32_t)k * 128u + (rows & 127u)) * 32u);
    }
  VMW(0);
  asm volatile("s_waitcnt lgkmcnt(0)" ::: "memory");
  __builtin_amdgcn_s_barrier();

  f32x4 acc[4][8] = {};

  auto STEP = [&](short8 (&CUR)[3][4], short8 (&NXT)[3][4], int cc, bool pre) {
    const uint8_t* bb = lds + (uint32_t)(cc & 1) * 8448u;
    if (pre) {                         // stage B(cc+1) into alt buffer FIRST
      const uint16_t* xs = xBase + (size_t)(cc + 1) * 4096;
      uint8_t* bw = lds + (uint32_t)((cc + 1) & 1) * 8448u + 128u;
#pragma unroll
      for (int t = 0; t < SLD; ++t)
        async_copy16(xs + (t * NT + tid) * 8, bw + (uint32_t)(t * NT + tid) * 16);
      SB;                              // pin issue order: B-stage before A loads
    }
    const uint16_t* aP = wLane + (size_t)(cc + 1) * AST;
#pragma unroll
    for (int k = 0; k < 3; ++k) {
      if (pre) {                       // staggered A prefetch for chunk cc+1
#pragma unroll
        for (int q = 0; q < 4; ++q) {
          uint32_t rows = (uint32_t)(wv * 64 + q * 16);
          NXT[k][q] = *(const short8*)(aP + (rows >> 7) * 12288u +
                                       ((uint32_t)k * 128u + (rows & 127u)) * 32u);
        }
      }
      short8 bf[8];
#pragma unroll
      for (int bq = 0; bq < 8; ++bq) {
        uint32_t r = (uint32_t)(bq * 16 + l15 + 2 * k);   // l' = l + 2k
        bf[bq] = *(const short8*)(bb + r * 64u +
                                  (((uint32_t)kg ^ (r >> 1)) & 3u) * 16u);
      }
      __builtin_amdgcn_s_setprio(1);
#pragma unroll
      for (int q = 0; q < 4; ++q)
#pragma unroll
        for (int bq = 0; bq < 8; ++bq)
          acc[q][bq] = __builtin_amdgcn_mfma_f32_16x16x32_bf16(
              CUR[k][q], bf[bq], acc[q][bq], 0, 0, 0);
      __builtin_amdgcn_s_setprio(0);
    }
    if (pre) {
      VMW(12);                         // B-stage retired; 12 A stay in flight
      __builtin_amdgcn_s_barrier();    // bare: no vm/lgkm drain
    }
  };

#pragma unroll 1
  for (int cc = 0; cc < CC - 2; cc += 2) {
    STEP(aA, aB, cc, true);
    STEP(aB, aA, cc + 1, true);
  }
  STEP(aA, aB, CC - 2, true);
  STEP(aB, aA, CC - 1, false);

  if (PHASE == 1) {
    // bias + gelu + bf16, write h_prep's swizzled chunk layout
#pragma unroll
    for (int a = 0; a < 4; ++a) {
      int ob = mt * 256 + wv * 64 + a * 16 + kg * 4;
      float4 bv = *(const float4*)(bias + (size_t)e * OO + ob);
      int cc2 = mt * 8 + wv * 2 + (a >> 1);
      uint32_t g = (uint32_t)((a & 1) * 2 + (kg >> 1));
      uint32_t j0 = (uint32_t)((kg & 1) * 4);
#pragma unroll
      for (int bq = 0; bq < 8; ++bq) {
        int l = bq * 16 + l15;
        uint32_t flq = ((uint32_t)(l + 2) >> 1) & 3u;
        uint32_t sub = g ^ flq;
        float v0 = gelu_f(acc[a][bq][0] + bv.x);
        float v1 = gelu_f(acc[a][bq][1] + bv.y);
        float v2 = gelu_f(acc[a][bq][2] + bv.z);
        float v3 = gelu_f(acc[a][bq][3] + bv.w);
        uint2 pk;
        pk.x = (uint32_t)f2bf(v0) | ((uint32_t)f2bf(v1) << 16);
        pk.y = (uint32_t)f2bf(v2) | ((uint32_t)f2bf(v3) << 16);
        size_t ci = ((size_t)s * 32 + cc2) * 128 + l;
        *(uint2*)(hout + ci * 32 + sub * 8 + j0) = pk;
      }
    }
  } else {
#pragma unroll
    for (int a = 0; a < 4; ++a) {
      int ob = mt * 128 + wv * 64 + a * 16 + kg * 4;
      float4 bv = *(const float4*)(bias + (size_t)e * OO + ob);
      float bvr[4] = {bv.x, bv.y, bv.z, bv.w};
      float* op = fout + ((size_t)s * DMV + ob) * 128;
#pragma unroll
      for (int bq = 0; bq < 8; ++bq) {
        int l = bq * 16 + l15;
#pragma unroll
        for (int r = 0; r < 4; ++r)
          op[(size_t)r * 128 + l] = acc[a][bq][r] + bvr[r];
      }
    }
  }
}

extern "C" void kernel_launch(void* const* d_in, const int* in_sizes, int n_in,
                              void* d_out, int out_size, void* d_ws, size_t ws_size,
                              hipStream_t stream) {
  const float* inp = (const float*)d_in[0];
  const int* cnt = (const int*)d_in[1];
  const float* w1 = (const float*)d_in[2];
  const float* b1 = (const float*)d_in[3];
  const float* w2 = (const float*)d_in[4];
  const float* b2 = (const float*)d_in[5];
  float* out = (float*)d_out;
  uint8_t* ws = (uint8_t*)d_ws;
  uint16_t* xp = (uint16_t*)(ws + OFF_X);
  uint16_t* hp = (uint16_t*)(ws + OFF_H);
  uint16_t* w1p = (uint16_t*)(ws + OFF_W1);
  uint16_t* w2p = (uint16_t*)(ws + OFF_W2);

  prep_x_t<<<dim3(2048), dim3(256), 0, stream>>>(inp, xp);
  prep_w_c<7, 10><<<dim3(4096), dim3(256), 0, stream>>>(w1, w1p);
  prep_w_c<8, 9><<<dim3(4096), dim3(256), 0, stream>>>(w2, w2p);
  conv_mfma<1><<<dim3(512), dim3(256), 0, stream>>>(xp, w1p, b1, cnt, hp, nullptr);
  conv_mfma<2><<<dim3(512), dim3(128), 0, stream>>>(hp, w2p, b2, cnt, nullptr, out);
}